// Round 1
// baseline (617.402 us; speedup 1.0000x reference)
//
#include <hip/hip_runtime.h>
#include <math.h>

// ---------------- problem constants ----------------
#define NCLS 19
#define DD   128
#define EPSV 1e-7f
#define LOGEPS -16.118095651f   // ln(1e-7)

// ---------------- workspace layout (float indices) ----------------
#define OFF_TAU    0
#define OFF_CNTL   8      // 19
#define OFF_WSUMU  32     // 19
#define OFF_CNTU   64     // 19
#define OFF_CE     96     // 4
#define OFF_VALID  100    // 4
#define OFF_UCPS   104    // 1
#define OFF_SUML   128    // 19*128 = 2432
#define OFF_SUMU   2560   // 2432
#define OFF_MEM    4992   // 2432
#define OFF_INIT   7424   // 19
#define OFF_RUD    7456   // 4*128*128 = 65536
#define OFF_PSEUDO 72992  // 65536 ints
#define ZERO_N     72992  // zero [0, OFF_PSEUDO)
// total ws use: (72992 + 65536) * 4 B = 554112 B

__device__ __forceinline__ void fatom(float* p, float v) { unsafeAtomicAdd(p, v); }

// ---------------- kZ: zero accumulators + tau_high ----------------
__global__ __launch_bounds__(256) void kZ(float* __restrict__ W,
                                          const int* __restrict__ cur_it,
                                          const int* __restrict__ max_it) {
    int i = blockIdx.x * 256 + threadIdx.x;
    if (i == 0) {
        int mi = max_it[0]; if (mi < 1) mi = 1;
        double ratio = (double)cur_it[0] / (double)mi;
        W[OFF_TAU] = (float)(0.85 - (0.85 - 0.5) * cos(M_PI * ratio * 0.5));
    } else if (i < ZERO_N) {
        W[i] = 0.0f;
    }
}

// ---------------- kB: reliability map + UCPS loss + pseudo labels ----------------
// grid 4096 x 256; one thread per logit pixel (b,h,w)
__global__ __launch_bounds__(256) void kB(const float* __restrict__ lu1,
                                          const float* __restrict__ lu2,
                                          float* __restrict__ W) {
    float* rud = W + OFF_RUD;
    int* pseudo = (int*)(W + OFF_PSEUDO);
    int t = blockIdx.x * 256 + threadIdx.x;
    int b = t >> 18;            // 512*512 = 262144
    int rem = t & 262143;
    int h = rem >> 9, w = rem & 511;
    const float* p1 = lu1 + (size_t)b * (NCLS * 262144) + rem;
    const float* p2 = lu2 + (size_t)b * (NCLS * 262144) + rem;

    float v1[NCLS], v2[NCLS];
#pragma unroll
    for (int c = 0; c < NCLS; c++) v1[c] = p1[(size_t)c * 262144];
#pragma unroll
    for (int c = 0; c < NCLS; c++) v2[c] = p2[(size_t)c * 262144];

    float m1 = v1[0]; int y1 = 0;
    float m2 = v2[0]; int y2 = 0;
#pragma unroll
    for (int c = 1; c < NCLS; c++) {
        if (v1[c] > m1) { m1 = v1[c]; y1 = c; }
        if (v2[c] > m2) { m2 = v2[c]; y2 = c; }
    }
    float s1 = 0.f, s2 = 0.f;
#pragma unroll
    for (int c = 0; c < NCLS; c++) { s1 += __expf(v1[c] - m1); s2 += __expf(v2[c] - m2); }
    float lse1 = m1 + __logf(s1);
    float lse2 = m2 + __logf(s2);

    float kl = 0.f, l1y2 = v1[0], l2y1 = v2[0];
#pragma unroll
    for (int c = 0; c < NCLS; c++) {
        float lq1 = v1[c] - lse1, lq2 = v2[c] - lse2;
        float q1 = __expf(lq1), q2 = __expf(lq2);
        float mm = 0.5f * (q1 + q2);
        float lm = __logf(fmaxf(mm, EPSV));
        kl += q1 * (fmaxf(lq1, LOGEPS) - lm) + q2 * (fmaxf(lq2, LOGEPS) - lm);
        if (c == y2) l1y2 = v1[c];
        if (c == y1) l2y1 = v2[c];
    }
    float conf = 0.5f * (1.f / s1 + 1.f / s2);                 // max softmax probs
    float r_u = (y1 == y2) ? conf * __expf(-0.5f * kl) : 0.f;
    float ce = (lse1 - l1y2) + (lse2 - l2y1);
    float contrib = r_u * ce;

    __shared__ float red[256];
    red[threadIdx.x] = contrib;
    __syncthreads();
    for (int s = 128; s > 0; s >>= 1) {
        if (threadIdx.x < s) red[threadIdx.x] += red[threadIdx.x + s];
        __syncthreads();
    }
    if (threadIdx.x == 0) fatom(&W[OFF_UCPS], red[0]);

    int hm = h & 3, wm = w & 3;
    // bilinear 4x down (half-pixel): out(i,j) = mean of r_u at rows/cols {4i+1,4i+2}
    if ((hm == 1 || hm == 2) && (wm == 1 || wm == 2))
        fatom(&rud[b * 16384 + (h >> 2) * 128 + (w >> 2)], 0.25f * r_u);
    // nearest down at (4i,4j): consensus pseudo label
    if (hm == 0 && wm == 0)
        pseudo[b * 16384 + (h >> 2) * 128 + (w >> 2)] = (y1 == y2) ? y1 : 0;
}

// ---------------- kC: prototype accumulation (segment sums) ----------------
// grid 64 x 256, 4 pixels/thread. LDS class-row stride 129 -> bank (c+d)%32.
__global__ __launch_bounds__(256) void kC(const float* __restrict__ fl1,
                                          const float* __restrict__ fl2,
                                          const float* __restrict__ fu1,
                                          const float* __restrict__ fu2,
                                          const int* __restrict__ gt,
                                          float* __restrict__ W) {
    __shared__ float sL[NCLS * 129];
    __shared__ float sU[NCLS * 129];
    __shared__ float sCntL[NCLS], sWU[NCLS], sCntU[NCLS];
    for (int i = threadIdx.x; i < NCLS * 129; i += 256) { sL[i] = 0.f; sU[i] = 0.f; }
    if (threadIdx.x < NCLS) { sCntL[threadIdx.x] = 0.f; sWU[threadIdx.x] = 0.f; sCntU[threadIdx.x] = 0.f; }
    __syncthreads();

    const float tau = W[OFF_TAU];
    const float* rud = W + OFF_RUD;
    const int* pseudo = (const int*)(W + OFF_PSEUDO);

    for (int k = 0; k < 4; k++) {
        int p = k * 16384 + blockIdx.x * 256 + threadIdx.x;
        int b = p >> 14;
        int rem = p & 16383;
        int i = rem >> 7, j = rem & 127;
        int cl = gt[b * 262144 + i * 2048 + j * 4];   // gt at (4i,4j)
        int cu = pseudo[p];
        float rd = rud[p];
        float wgt = (rd > tau) ? rd : 0.f;
        fatom(&sCntL[cl], 1.f);
        fatom(&sCntU[cu], 1.f);
        if (wgt > 0.f) fatom(&sWU[cu], wgt);
        size_t base = (size_t)b * 2097152 + rem;
        float* rowL = &sL[cl * 129];
        float* rowU = &sU[cu * 129];
        if (wgt > 0.f) {
#pragma unroll 4
            for (int d = 0; d < DD; d++) {
                size_t idx = base + (size_t)d * 16384;
                fatom(&rowL[d], 0.5f * (fl1[idx] + fl2[idx]));
                fatom(&rowU[d], wgt * 0.5f * (fu1[idx] + fu2[idx]));
            }
        } else {
#pragma unroll 4
            for (int d = 0; d < DD; d++) {
                size_t idx = base + (size_t)d * 16384;
                fatom(&rowL[d], 0.5f * (fl1[idx] + fl2[idx]));
            }
        }
    }
    __syncthreads();
    for (int i = threadIdx.x; i < NCLS * DD; i += 256) {
        int c = i >> 7, d = i & 127;
        fatom(&W[OFF_SUML + i], sL[c * 129 + d]);
        fatom(&W[OFF_SUMU + i], sU[c * 129 + d]);
    }
    if (threadIdx.x < NCLS) {
        fatom(&W[OFF_CNTL + threadIdx.x], sCntL[threadIdx.x]);
        fatom(&W[OFF_WSUMU + threadIdx.x], sWU[threadIdx.x]);
        fatom(&W[OFF_CNTU + threadIdx.x], sCntU[threadIdx.x]);
    }
}

// ---------------- kD: finalize prototypes + memory update ----------------
// grid 19 x 128 (one block per class, one thread per d)
__global__ __launch_bounds__(128) void kD(const float* __restrict__ mem,
                                          const unsigned char* __restrict__ minit,
                                          float* __restrict__ W) {
    int c = blockIdx.x, d = threadIdx.x;
    __shared__ float red[128];
    float cntL = W[OFF_CNTL + c], wsU = W[OFF_WSUMU + c], cntU = W[OFF_CNTU + c];
    bool plp = cntL >= 1.f, pup = cntU >= 1.f;
    float pl = W[OFF_SUML + c * DD + d] / (cntL + EPSV);
    float pu = W[OFF_SUMU + c * DD + d] / (wsU + EPSV);
    float merged = (plp && pup) ? (0.7f * pl + 0.3f * pu) : (plp ? pl : pu);

    red[d] = merged * merged; __syncthreads();
    for (int s = 64; s > 0; s >>= 1) { if (d < s) red[d] += red[d + s]; __syncthreads(); }
    float nrm = red[0];
    __syncthreads();
    float pn = merged / fmaxf(sqrtf(nrm), 1e-12f);

    float mo = mem[c * DD + d];
    float e = 0.999f * mo + 0.001f * pn;
    red[d] = e * e; __syncthreads();
    for (int s = 64; s > 0; s >>= 1) { if (d < s) red[d] += red[d + s]; __syncthreads(); }
    float ne = red[0];
    float ema = e / fmaxf(sqrtf(ne), 1e-12f);

    bool present = plp || pup;
    bool init = (minit[c] != 0);   // all-False input: zero bytes either dtype width
    float nm = present ? (init ? ema : pn) : mo;
    W[OFF_MEM + c * DD + d] = nm;
    if (d == 0) W[OFF_INIT + c] = (init || present) ? 1.f : 0.f;
}

// ---------------- kE: hard contrastive for 4 feats ----------------
__device__ __forceinline__ void pix_loss(const float dots[NCLS], float nn, int lab,
                                         const float* sInit, float& ce_acc, float& v_acc) {
    float inv = 5.0f / fmaxf(sqrtf(nn), 1e-12f);   // 1/TAU_HARD = 5
    float lg[NCLS];
#pragma unroll
    for (int c = 0; c < NCLS; c++) lg[c] = dots[c] * inv;
    float mx = lg[0];
#pragma unroll
    for (int c = 1; c < NCLS; c++) mx = fmaxf(mx, lg[c]);
    float s = 0.f;
#pragma unroll
    for (int c = 0; c < NCLS; c++) s += __expf(lg[c] - mx);
    float lse = mx + __logf(s);
    float ll = lg[0];
#pragma unroll
    for (int c = 1; c < NCLS; c++) if (c == lab) ll = lg[c];
    float vld = sInit[lab];
    ce_acc += vld * (lse - ll);
    v_acc += vld;
}

// grid (128, 4) x 256; thread handles pixels p0 and p0+256 of feat blockIdx.y
__global__ __launch_bounds__(256) void kE(const float* __restrict__ f0,
                                          const float* __restrict__ f1,
                                          const float* __restrict__ f2,
                                          const float* __restrict__ f3,
                                          const int* __restrict__ gt,
                                          float* __restrict__ W) {
    __shared__ __align__(16) float sMem[NCLS * DD];
    __shared__ float sInit[NCLS];
    __shared__ float redA[256], redB[256];
    int fid = blockIdx.y;
    const float* feat = (fid == 0) ? f0 : (fid == 1) ? f1 : (fid == 2) ? f2 : f3;
    for (int i = threadIdx.x; i < NCLS * DD; i += 256) sMem[i] = W[OFF_MEM + i];
    if (threadIdx.x < NCLS) sInit[threadIdx.x] = W[OFF_INIT + threadIdx.x];
    __syncthreads();

    int p0 = blockIdx.x * 512 + threadIdx.x;   // second pixel = p0 + 256 (same b)
    int b = p0 >> 14;
    int rem0 = p0 & 16383;
    const float* fp = feat + (size_t)b * 2097152 + rem0;

    float dots0[NCLS], dots1[NCLS];
#pragma unroll
    for (int c = 0; c < NCLS; c++) { dots0[c] = 0.f; dots1[c] = 0.f; }
    float n0 = 0.f, n1 = 0.f;

    for (int d0 = 0; d0 < DD; d0 += 4) {
        const float* fpp = fp + (size_t)d0 * 16384;
        float a0 = fpp[0],     a1 = fpp[16384],       a2 = fpp[32768],       a3 = fpp[49152];
        float b0 = fpp[256],   b1 = fpp[16384 + 256], b2 = fpp[32768 + 256], b3 = fpp[49152 + 256];
        n0 += a0 * a0 + a1 * a1 + a2 * a2 + a3 * a3;
        n1 += b0 * b0 + b1 * b1 + b2 * b2 + b3 * b3;
#pragma unroll
        for (int c = 0; c < NCLS; c++) {
            float4 mv = *(const float4*)&sMem[c * DD + d0];
            dots0[c] += a0 * mv.x + a1 * mv.y + a2 * mv.z + a3 * mv.w;
            dots1[c] += b0 * mv.x + b1 * mv.y + b2 * mv.z + b3 * mv.w;
        }
    }

    const int* pseudo = (const int*)(W + OFF_PSEUDO);
    int rem1 = rem0 + 256;
    int lab0 = (fid < 2) ? gt[b * 262144 + (rem0 >> 7) * 2048 + (rem0 & 127) * 4] : pseudo[p0];
    int lab1 = (fid < 2) ? gt[b * 262144 + (rem1 >> 7) * 2048 + (rem1 & 127) * 4] : pseudo[p0 + 256];

    float ce_acc = 0.f, v_acc = 0.f;
    pix_loss(dots0, n0, lab0, sInit, ce_acc, v_acc);
    pix_loss(dots1, n1, lab1, sInit, ce_acc, v_acc);

    redA[threadIdx.x] = ce_acc;
    redB[threadIdx.x] = v_acc;
    __syncthreads();
    for (int s = 128; s > 0; s >>= 1) {
        if (threadIdx.x < s) { redA[threadIdx.x] += redA[threadIdx.x + s]; redB[threadIdx.x] += redB[threadIdx.x + s]; }
        __syncthreads();
    }
    if (threadIdx.x == 0) {
        fatom(&W[OFF_CE + fid], redA[0]);
        fatom(&W[OFF_VALID + fid], redB[0]);
    }
}

// ---------------- kF: combine -> d_out[2] ----------------
__global__ void kF(float* __restrict__ out, const float* __restrict__ W) {
    if (threadIdx.x == 0 && blockIdx.x == 0) {
        float h[4];
#pragma unroll
        for (int i = 0; i < 4; i++) {
            float nv = W[OFF_VALID + i];
            h[i] = (nv > 0.f) ? W[OFF_CE + i] / fmaxf(nv, 1.f) : 0.f;
        }
        out[0] = 0.5f * (h[0] + h[1]) + 0.5f * (h[2] + h[3]);   // loss_dgpc
        out[1] = W[OFF_UCPS] * (1.0f / 1048576.0f);             // loss_ucps
    }
}

extern "C" void kernel_launch(void* const* d_in, const int* in_sizes, int n_in,
                              void* d_out, int out_size, void* d_ws, size_t ws_size,
                              hipStream_t stream) {
    const float* fl1 = (const float*)d_in[0];
    const float* fl2 = (const float*)d_in[1];
    const float* fu1 = (const float*)d_in[2];
    const float* fu2 = (const float*)d_in[3];
    // d_in[4], d_in[5] (logits_l1/l2) are unused by the reference
    const float* lu1 = (const float*)d_in[6];
    const float* lu2 = (const float*)d_in[7];
    const float* mem = (const float*)d_in[8];
    const int* gt = (const int*)d_in[9];
    const unsigned char* minit = (const unsigned char*)d_in[10];
    const int* cur = (const int*)d_in[11];
    const int* mxi = (const int*)d_in[12];
    float* W = (float*)d_ws;
    float* out = (float*)d_out;

    kZ<<<286, 256, 0, stream>>>(W, cur, mxi);
    kB<<<4096, 256, 0, stream>>>(lu1, lu2, W);
    kC<<<64, 256, 0, stream>>>(fl1, fl2, fu1, fu2, gt, W);
    kD<<<NCLS, 128, 0, stream>>>(mem, minit, W);
    kE<<<dim3(128, 4), 256, 0, stream>>>(fl1, fl2, fu1, fu2, gt, W);
    kF<<<1, 64, 0, stream>>>(out, W);
}

// Round 2
// 430.053 us; speedup vs baseline: 1.4356x; 1.4356x over previous
//
#include <hip/hip_runtime.h>
#include <math.h>

// ---------------- problem constants ----------------
#define NCLS 19
#define DD   128
#define EPSV 1e-7f
#define LOGEPS -16.118095651f   // ln(1e-7)

// ---------------- workspace layout (float indices) ----------------
#define OFF_TAU    0
#define OFF_CNTL   8      // 19
#define OFF_WSUMU  32     // 19
#define OFF_CNTU   64     // 19
#define OFF_CE     96     // 4
#define OFF_VALID  100    // 4
#define OFF_UCPS   104    // 1
#define OFF_SUML   128    // 19*128 = 2432
#define OFF_SUMU   2560   // 2432
#define OFF_MEM    4992   // 2432
#define OFF_INIT   7424   // 19
#define OFF_RUD    7456   // 4*128*128 = 65536
#define OFF_PSEUDO 72992  // 65536 ints
#define ZERO_N     72992  // zero [0, OFF_PSEUDO)

__device__ __forceinline__ void fatom(float* p, float v) { unsafeAtomicAdd(p, v); }

// ---------------- kZ: zero accumulators + tau_high ----------------
__global__ __launch_bounds__(256) void kZ(float* __restrict__ W,
                                          const int* __restrict__ cur_it,
                                          const int* __restrict__ max_it) {
    int i = blockIdx.x * 256 + threadIdx.x;
    if (i == 0) {
        int mi = max_it[0]; if (mi < 1) mi = 1;
        double ratio = (double)cur_it[0] / (double)mi;
        W[OFF_TAU] = (float)(0.85 - (0.85 - 0.5) * cos(M_PI * ratio * 0.5));
    } else if (i < ZERO_N) {
        W[i] = 0.0f;
    }
}

// ---------------- kB: reliability map + UCPS loss + pseudo labels ----------------
// grid 4096 x 256; one thread per logit pixel (b,h,w)
__global__ __launch_bounds__(256) void kB(const float* __restrict__ lu1,
                                          const float* __restrict__ lu2,
                                          float* __restrict__ W) {
    float* rud = W + OFF_RUD;
    int* pseudo = (int*)(W + OFF_PSEUDO);
    int t = blockIdx.x * 256 + threadIdx.x;
    int b = t >> 18;            // 512*512 = 262144
    int rem = t & 262143;
    int h = rem >> 9, w = rem & 511;
    const float* p1 = lu1 + (size_t)b * (NCLS * 262144) + rem;
    const float* p2 = lu2 + (size_t)b * (NCLS * 262144) + rem;

    float v1[NCLS], v2[NCLS];
#pragma unroll
    for (int c = 0; c < NCLS; c++) v1[c] = p1[(size_t)c * 262144];
#pragma unroll
    for (int c = 0; c < NCLS; c++) v2[c] = p2[(size_t)c * 262144];

    float m1 = v1[0]; int y1 = 0;
    float m2 = v2[0]; int y2 = 0;
#pragma unroll
    for (int c = 1; c < NCLS; c++) {
        if (v1[c] > m1) { m1 = v1[c]; y1 = c; }
        if (v2[c] > m2) { m2 = v2[c]; y2 = c; }
    }
    float s1 = 0.f, s2 = 0.f;
#pragma unroll
    for (int c = 0; c < NCLS; c++) { s1 += __expf(v1[c] - m1); s2 += __expf(v2[c] - m2); }
    float lse1 = m1 + __logf(s1);
    float lse2 = m2 + __logf(s2);

    float kl = 0.f, l1y2 = v1[0], l2y1 = v2[0];
#pragma unroll
    for (int c = 0; c < NCLS; c++) {
        float lq1 = v1[c] - lse1, lq2 = v2[c] - lse2;
        float q1 = __expf(lq1), q2 = __expf(lq2);
        float mm = 0.5f * (q1 + q2);
        float lm = __logf(fmaxf(mm, EPSV));
        kl += q1 * (fmaxf(lq1, LOGEPS) - lm) + q2 * (fmaxf(lq2, LOGEPS) - lm);
        if (c == y2) l1y2 = v1[c];
        if (c == y1) l2y1 = v2[c];
    }
    float conf = 0.5f * (1.f / s1 + 1.f / s2);                 // max softmax probs
    float r_u = (y1 == y2) ? conf * __expf(-0.5f * kl) : 0.f;
    float ce = (lse1 - l1y2) + (lse2 - l2y1);
    float contrib = r_u * ce;

    __shared__ float red[256];
    red[threadIdx.x] = contrib;
    __syncthreads();
    for (int s = 128; s > 0; s >>= 1) {
        if (threadIdx.x < s) red[threadIdx.x] += red[threadIdx.x + s];
        __syncthreads();
    }
    if (threadIdx.x == 0) fatom(&W[OFF_UCPS], red[0]);

    int hm = h & 3, wm = w & 3;
    // bilinear 4x down (half-pixel): out(i,j) = mean of r_u at rows/cols {4i+1,4i+2}
    if ((hm == 1 || hm == 2) && (wm == 1 || wm == 2))
        fatom(&rud[b * 16384 + (h >> 2) * 128 + (w >> 2)], 0.25f * r_u);
    // nearest down at (4i,4j): consensus pseudo label
    if (hm == 0 && wm == 0)
        pseudo[b * 16384 + (h >> 2) * 128 + (w >> 2)] = (y1 == y2) ? y1 : 0;
}

// ---------------- kC v2: transposed segment-sum, zero hot-loop atomics ----------
// grid 512 x 256. Block owns 128 consecutive pixels (4 tiles of 32).
// Thread (pg = tid>>7, d = tid&127) exclusively owns accum column (pg, :, d):
// all lanes of a wave share pixel p / class row but have distinct d -> no
// collisions, 2-way bank alias only (free). Staging is coalesced; rare
// anchor pixels (w>0, wave-uniform test) gather fu directly from global.
__global__ __launch_bounds__(256) void kC(const float* __restrict__ fl1,
                                          const float* __restrict__ fl2,
                                          const float* __restrict__ fu1,
                                          const float* __restrict__ fu2,
                                          const int* __restrict__ gt,
                                          float* __restrict__ W) {
    __shared__ float tile[DD * 33];        // [d][p], pad 33 -> bank (d+p)%32
    __shared__ float accL[2 * NCLS * DD];  // [pg][c][d]
    __shared__ float accU[2 * NCLS * DD];
    __shared__ int   sLab[32], sCu[32];
    __shared__ float sW[32];
    __shared__ float sCntL[NCLS], sCntU[NCLS], sWUs[NCLS];
    __shared__ int   sAny;

    int tid = threadIdx.x;
    for (int i = tid; i < 2 * NCLS * DD; i += 256) { accL[i] = 0.f; accU[i] = 0.f; }
    if (tid < NCLS) { sCntL[tid] = 0.f; sCntU[tid] = 0.f; sWUs[tid] = 0.f; }
    if (tid == 0) sAny = 0;
    __syncthreads();

    int P0 = blockIdx.x * 128;             // flat pixel start (b*16384 + rem)
    int b = P0 >> 14;
    const float tau = W[OFF_TAU];
    const float* rud = W + OFF_RUD;
    const int* pseudo = (const int*)(W + OFF_PSEUDO);
    size_t gb = (size_t)b * 2097152;

    int d = tid & 127, pg = tid >> 7;

    for (int T = 0; T < 4; T++) {
        int rem0 = (P0 + T * 32) & 16383;
        // ---- label/weight phase (32 threads) + stage (all threads) ----
        if (tid < 32) {
            int rem = rem0 + tid;
            int bp = b * 16384 + rem;
            int ii = rem >> 7, jj = rem & 127;
            int cl = gt[b * 262144 + ii * 2048 + jj * 4];
            int cu = pseudo[bp];
            float rd = rud[bp];
            float w = (rd > tau) ? rd : 0.f;
            sLab[tid] = cl; sCu[tid] = cu; sW[tid] = w;
            fatom(&sCntL[cl], 1.f);
            fatom(&sCntU[cu], 1.f);
            if (w > 0.f) { fatom(&sWUs[cu], w); sAny = 1; }
        }
        for (int i = tid; i < 32 * DD; i += 256) {
            int dd = i >> 5, p = i & 31;
            size_t g = gb + (size_t)dd * 16384 + rem0 + p;
            tile[dd * 33 + p] = 0.5f * (fl1[g] + fl2[g]);
        }
        __syncthreads();
        // ---- transposed accumulate: zero atomics ----
        float* aL = &accL[pg * (NCLS * DD) + d];
        float* aU = &accU[pg * (NCLS * DD) + d];
#pragma unroll
        for (int p = pg * 16; p < pg * 16 + 16; p++) {
            int c = sLab[p];
            aL[c * DD] += tile[d * 33 + p];
            float w = sW[p];
            if (w > 0.f) {                 // wave-uniform branch, rare
                size_t g = gb + (size_t)d * 16384 + rem0 + p;
                aU[sCu[p] * DD] += w * 0.5f * (fu1[g] + fu2[g]);
            }
        }
        __syncthreads();
    }
    // ---- flush per-block partials ----
    for (int i = tid; i < NCLS * DD; i += 256)
        fatom(&W[OFF_SUML + i], accL[i] + accL[NCLS * DD + i]);
    if (sAny)
        for (int i = tid; i < NCLS * DD; i += 256)
            fatom(&W[OFF_SUMU + i], accU[i] + accU[NCLS * DD + i]);
    if (tid < NCLS) {
        fatom(&W[OFF_CNTL + tid], sCntL[tid]);
        fatom(&W[OFF_WSUMU + tid], sWUs[tid]);
        fatom(&W[OFF_CNTU + tid], sCntU[tid]);
    }
}

// ---------------- kD: finalize prototypes + memory update ----------------
// grid 19 x 128 (one block per class, one thread per d)
__global__ __launch_bounds__(128) void kD(const float* __restrict__ mem,
                                          const unsigned char* __restrict__ minit,
                                          float* __restrict__ W) {
    int c = blockIdx.x, d = threadIdx.x;
    __shared__ float red[128];
    float cntL = W[OFF_CNTL + c], wsU = W[OFF_WSUMU + c], cntU = W[OFF_CNTU + c];
    bool plp = cntL >= 1.f, pup = cntU >= 1.f;
    float pl = W[OFF_SUML + c * DD + d] / (cntL + EPSV);
    float pu = W[OFF_SUMU + c * DD + d] / (wsU + EPSV);
    float merged = (plp && pup) ? (0.7f * pl + 0.3f * pu) : (plp ? pl : pu);

    red[d] = merged * merged; __syncthreads();
    for (int s = 64; s > 0; s >>= 1) { if (d < s) red[d] += red[d + s]; __syncthreads(); }
    float nrm = red[0];
    __syncthreads();
    float pn = merged / fmaxf(sqrtf(nrm), 1e-12f);

    float mo = mem[c * DD + d];
    float e = 0.999f * mo + 0.001f * pn;
    red[d] = e * e; __syncthreads();
    for (int s = 64; s > 0; s >>= 1) { if (d < s) red[d] += red[d + s]; __syncthreads(); }
    float ne = red[0];
    float ema = e / fmaxf(sqrtf(ne), 1e-12f);

    bool present = plp || pup;
    bool init = (minit[c] != 0);   // all-False input: zero bytes either dtype width
    float nm = present ? (init ? ema : pn) : mo;
    W[OFF_MEM + c * DD + d] = nm;
    if (d == 0) W[OFF_INIT + c] = (init || present) ? 1.f : 0.f;
}

// ---------------- kE: hard contrastive for 4 feats ----------------
__device__ __forceinline__ void pix_loss(const float dots[NCLS], float nn, int lab,
                                         const float* sInit, float& ce_acc, float& v_acc) {
    float inv = 5.0f / fmaxf(sqrtf(nn), 1e-12f);   // 1/TAU_HARD = 5
    float lg[NCLS];
#pragma unroll
    for (int c = 0; c < NCLS; c++) lg[c] = dots[c] * inv;
    float mx = lg[0];
#pragma unroll
    for (int c = 1; c < NCLS; c++) mx = fmaxf(mx, lg[c]);
    float s = 0.f;
#pragma unroll
    for (int c = 0; c < NCLS; c++) s += __expf(lg[c] - mx);
    float lse = mx + __logf(s);
    float ll = lg[0];
#pragma unroll
    for (int c = 1; c < NCLS; c++) if (c == lab) ll = lg[c];
    float vld = sInit[lab];
    ce_acc += vld * (lse - ll);
    v_acc += vld;
}

// grid (128, 4) x 256; thread handles pixels p0 and p0+256 of feat blockIdx.y
__global__ __launch_bounds__(256) void kE(const float* __restrict__ f0,
                                          const float* __restrict__ f1,
                                          const float* __restrict__ f2,
                                          const float* __restrict__ f3,
                                          const int* __restrict__ gt,
                                          float* __restrict__ W) {
    __shared__ __align__(16) float sMem[NCLS * DD];
    __shared__ float sInit[NCLS];
    __shared__ float redA[256], redB[256];
    int fid = blockIdx.y;
    const float* feat = (fid == 0) ? f0 : (fid == 1) ? f1 : (fid == 2) ? f2 : f3;
    for (int i = threadIdx.x; i < NCLS * DD; i += 256) sMem[i] = W[OFF_MEM + i];
    if (threadIdx.x < NCLS) sInit[threadIdx.x] = W[OFF_INIT + threadIdx.x];
    __syncthreads();

    int p0 = blockIdx.x * 512 + threadIdx.x;   // second pixel = p0 + 256 (same b)
    int b = p0 >> 14;
    int rem0 = p0 & 16383;
    const float* fp = feat + (size_t)b * 2097152 + rem0;

    float dots0[NCLS], dots1[NCLS];
#pragma unroll
    for (int c = 0; c < NCLS; c++) { dots0[c] = 0.f; dots1[c] = 0.f; }
    float n0 = 0.f, n1 = 0.f;

    for (int d0 = 0; d0 < DD; d0 += 4) {
        const float* fpp = fp + (size_t)d0 * 16384;
        float a0 = fpp[0],     a1 = fpp[16384],       a2 = fpp[32768],       a3 = fpp[49152];
        float b0 = fpp[256],   b1 = fpp[16384 + 256], b2 = fpp[32768 + 256], b3 = fpp[49152 + 256];
        n0 += a0 * a0 + a1 * a1 + a2 * a2 + a3 * a3;
        n1 += b0 * b0 + b1 * b1 + b2 * b2 + b3 * b3;
#pragma unroll
        for (int c = 0; c < NCLS; c++) {
            float4 mv = *(const float4*)&sMem[c * DD + d0];
            dots0[c] += a0 * mv.x + a1 * mv.y + a2 * mv.z + a3 * mv.w;
            dots1[c] += b0 * mv.x + b1 * mv.y + b2 * mv.z + b3 * mv.w;
        }
    }

    const int* pseudo = (const int*)(W + OFF_PSEUDO);
    int rem1 = rem0 + 256;
    int lab0 = (fid < 2) ? gt[b * 262144 + (rem0 >> 7) * 2048 + (rem0 & 127) * 4] : pseudo[p0];
    int lab1 = (fid < 2) ? gt[b * 262144 + (rem1 >> 7) * 2048 + (rem1 & 127) * 4] : pseudo[p0 + 256];

    float ce_acc = 0.f, v_acc = 0.f;
    pix_loss(dots0, n0, lab0, sInit, ce_acc, v_acc);
    pix_loss(dots1, n1, lab1, sInit, ce_acc, v_acc);

    redA[threadIdx.x] = ce_acc;
    redB[threadIdx.x] = v_acc;
    __syncthreads();
    for (int s = 128; s > 0; s >>= 1) {
        if (threadIdx.x < s) { redA[threadIdx.x] += redA[threadIdx.x + s]; redB[threadIdx.x] += redB[threadIdx.x + s]; }
        __syncthreads();
    }
    if (threadIdx.x == 0) {
        fatom(&W[OFF_CE + fid], redA[0]);
        fatom(&W[OFF_VALID + fid], redB[0]);
    }
}

// ---------------- kF: combine -> d_out[2] ----------------
__global__ void kF(float* __restrict__ out, const float* __restrict__ W) {
    if (threadIdx.x == 0 && blockIdx.x == 0) {
        float h[4];
#pragma unroll
        for (int i = 0; i < 4; i++) {
            float nv = W[OFF_VALID + i];
            h[i] = (nv > 0.f) ? W[OFF_CE + i] / fmaxf(nv, 1.f) : 0.f;
        }
        out[0] = 0.5f * (h[0] + h[1]) + 0.5f * (h[2] + h[3]);   // loss_dgpc
        out[1] = W[OFF_UCPS] * (1.0f / 1048576.0f);             // loss_ucps
    }
}

extern "C" void kernel_launch(void* const* d_in, const int* in_sizes, int n_in,
                              void* d_out, int out_size, void* d_ws, size_t ws_size,
                              hipStream_t stream) {
    const float* fl1 = (const float*)d_in[0];
    const float* fl2 = (const float*)d_in[1];
    const float* fu1 = (const float*)d_in[2];
    const float* fu2 = (const float*)d_in[3];
    // d_in[4], d_in[5] (logits_l1/l2) are unused by the reference
    const float* lu1 = (const float*)d_in[6];
    const float* lu2 = (const float*)d_in[7];
    const float* mem = (const float*)d_in[8];
    const int* gt = (const int*)d_in[9];
    const unsigned char* minit = (const unsigned char*)d_in[10];
    const int* cur = (const int*)d_in[11];
    const int* mxi = (const int*)d_in[12];
    float* W = (float*)d_ws;
    float* out = (float*)d_out;

    kZ<<<286, 256, 0, stream>>>(W, cur, mxi);
    kB<<<4096, 256, 0, stream>>>(lu1, lu2, W);
    kC<<<512, 256, 0, stream>>>(fl1, fl2, fu1, fu2, gt, W);
    kD<<<NCLS, 128, 0, stream>>>(mem, minit, W);
    kE<<<dim3(128, 4), 256, 0, stream>>>(fl1, fl2, fu1, fu2, gt, W);
    kF<<<1, 64, 0, stream>>>(out, W);
}

// Round 3
// 418.066 us; speedup vs baseline: 1.4768x; 1.0287x over previous
//
#include <hip/hip_runtime.h>
#include <math.h>

// ---------------- problem constants ----------------
#define NCLS 19
#define DD   128
#define EPSV 1e-7f
#define LOGEPS -16.118095651f   // ln(1e-7)

// ---------------- workspace layout (float indices) ----------------
#define OFF_TAU    0
#define OFF_CNTL   8      // 19
#define OFF_WSUMU  32     // 19
#define OFF_CNTU   64     // 19
#define OFF_CE     96     // 4
#define OFF_VALID  100    // 4
#define OFF_UCPS   104    // 1
#define OFF_SUML   128    // 19*128 = 2432
#define OFF_SUMU   2560   // 2432
#define OFF_MEM    4992   // 2432
#define OFF_INIT   7424   // 19
#define OFF_RUD    7456   // 4*128*128 = 65536
#define OFF_PSEUDO 72992  // 65536 ints
#define ZERO_N     72992  // zero [0, OFF_PSEUDO)

__device__ __forceinline__ void fatom(float* p, float v) { unsafeAtomicAdd(p, v); }

// ---------------- kZ: zero accumulators + tau_high ----------------
__global__ __launch_bounds__(256) void kZ(float* __restrict__ W,
                                          const int* __restrict__ cur_it,
                                          const int* __restrict__ max_it) {
    int i = blockIdx.x * 256 + threadIdx.x;
    if (i == 0) {
        int mi = max_it[0]; if (mi < 1) mi = 1;
        double ratio = (double)cur_it[0] / (double)mi;
        W[OFF_TAU] = (float)(0.85 - (0.85 - 0.5) * cos(M_PI * ratio * 0.5));
    } else if (i < ZERO_N) {
        W[i] = 0.0f;
    }
}

// ---------------- kB v3: 4 pixels/thread, float4 channel loads ----------------
// grid 1024 x 256; thread owns pixel quad [t*4, t*4+4) (same row, wm = 0..3)
__global__ __launch_bounds__(256, 2) void kB(const float* __restrict__ lu1,
                                             const float* __restrict__ lu2,
                                             float* __restrict__ W) {
    float* rud = W + OFF_RUD;
    int* pseudo = (int*)(W + OFF_PSEUDO);
    int t = blockIdx.x * 256 + threadIdx.x;     // quad index in [0, 262144)
    int b = t >> 16;                            // 65536 quads per image
    int rem4 = (t << 2) & 262143;               // first pixel flat index in image
    int h = rem4 >> 9, w0 = rem4 & 511;

    const float4* p1 = (const float4*)lu1 + (size_t)b * (NCLS * 65536) + (rem4 >> 2);
    const float4* p2 = (const float4*)lu2 + (size_t)b * (NCLS * 65536) + (rem4 >> 2);

    float4 v1[NCLS], v2[NCLS];
#pragma unroll
    for (int c = 0; c < NCLS; c++) v1[c] = p1[c * 65536];
#pragma unroll
    for (int c = 0; c < NCLS; c++) v2[c] = p2[c * 65536];
    const float* a1 = (const float*)v1;   // a1[c*4+e]
    const float* a2 = (const float*)v2;

    float contrib = 0.f;
    float ru12 = 0.f;        // ru[1] + ru[2] (for bilinear down)
    int pl0 = 0;             // pseudo label of element 0

#pragma unroll
    for (int e = 0; e < 4; e++) {
        float m1 = a1[e]; int y1 = 0;
        float m2 = a2[e]; int y2 = 0;
#pragma unroll
        for (int c = 1; c < NCLS; c++) {
            float x1 = a1[c * 4 + e], x2 = a2[c * 4 + e];
            if (x1 > m1) { m1 = x1; y1 = c; }
            if (x2 > m2) { m2 = x2; y2 = c; }
        }
        float s1 = 0.f, s2 = 0.f;
#pragma unroll
        for (int c = 0; c < NCLS; c++) {
            s1 += __expf(a1[c * 4 + e] - m1);
            s2 += __expf(a2[c * 4 + e] - m2);
        }
        float lse1 = m1 + __logf(s1);
        float lse2 = m2 + __logf(s2);

        float kl = 0.f, l1y2 = a1[e], l2y1 = a2[e];
#pragma unroll
        for (int c = 0; c < NCLS; c++) {
            float x1 = a1[c * 4 + e], x2 = a2[c * 4 + e];
            float lq1 = x1 - lse1, lq2 = x2 - lse2;
            float q1 = __expf(lq1), q2 = __expf(lq2);
            float mm = 0.5f * (q1 + q2);
            float lm = __logf(fmaxf(mm, EPSV));
            kl += q1 * (fmaxf(lq1, LOGEPS) - lm) + q2 * (fmaxf(lq2, LOGEPS) - lm);
            if (c == y2) l1y2 = x1;
            if (c == y1) l2y1 = x2;
        }
        float conf = 0.5f * (1.f / s1 + 1.f / s2);
        float r_u = (y1 == y2) ? conf * __expf(-0.5f * kl) : 0.f;
        float ce = (lse1 - l1y2) + (lse2 - l2y1);
        contrib += r_u * ce;
        if (e == 1 || e == 2) ru12 += r_u;
        if (e == 0) pl0 = (y1 == y2) ? y1 : 0;
    }

    // wave reduce -> 1 atomic per block
    float cs = contrib;
#pragma unroll
    for (int o = 32; o > 0; o >>= 1) cs += __shfl_down(cs, o, 64);
    __shared__ float wsum[4];
    if ((threadIdx.x & 63) == 0) wsum[threadIdx.x >> 6] = cs;
    __syncthreads();
    if (threadIdx.x == 0) fatom(&W[OFF_UCPS], wsum[0] + wsum[1] + wsum[2] + wsum[3]);

    int hm = h & 3;
    int didx = b * 16384 + (h >> 2) * 128 + (w0 >> 2);
    // bilinear 4x down: out(i,j) = mean of r_u at rows/cols {4i+1,4i+2}
    if (hm == 1 || hm == 2) fatom(&rud[didx], 0.25f * ru12);
    // nearest down at (4i,4j): consensus pseudo label
    if (hm == 0) pseudo[didx] = pl0;
}

// ---------------- kC v3: transposed segment-sum; accU -> direct global -------
// grid 512 x 256. Block owns 128 consecutive pixels (4 tiles of 32).
// Thread (pg = tid>>7, d = tid&127) exclusively owns accum column (pg, :, d).
__global__ __launch_bounds__(256) void kC(const float* __restrict__ fl1,
                                          const float* __restrict__ fl2,
                                          const float* __restrict__ fu1,
                                          const float* __restrict__ fu2,
                                          const int* __restrict__ gt,
                                          float* __restrict__ W) {
    __shared__ float tile[DD * 33];        // [d][p], pad 33 -> bank (d+p)%32
    __shared__ float accL[2 * NCLS * DD];  // [pg][c][d]
    __shared__ int   sLab[32], sCu[32];
    __shared__ float sW[32];
    __shared__ float sCntL[NCLS], sCntU[NCLS], sWUs[NCLS];

    int tid = threadIdx.x;
    for (int i = tid; i < 2 * NCLS * DD; i += 256) accL[i] = 0.f;
    if (tid < NCLS) { sCntL[tid] = 0.f; sCntU[tid] = 0.f; sWUs[tid] = 0.f; }
    __syncthreads();

    int P0 = blockIdx.x * 128;             // flat pixel start (b*16384 + rem)
    int b = P0 >> 14;
    const float tau = W[OFF_TAU];
    const float* rud = W + OFF_RUD;
    const int* pseudo = (const int*)(W + OFF_PSEUDO);
    size_t gb = (size_t)b * 2097152;

    int d = tid & 127, pg = tid >> 7;

    for (int T = 0; T < 4; T++) {
        int rem0 = (P0 + T * 32) & 16383;
        // ---- label/weight phase (32 threads) ----
        if (tid < 32) {
            int rem = rem0 + tid;
            int bp = b * 16384 + rem;
            int ii = rem >> 7, jj = rem & 127;
            int cl = gt[b * 262144 + ii * 2048 + jj * 4];
            int cu = pseudo[bp];
            float rd = rud[bp];
            float w = (rd > tau) ? rd : 0.f;
            sLab[tid] = cl; sCu[tid] = cu; sW[tid] = w;
            fatom(&sCntL[cl], 1.f);
            fatom(&sCntU[cu], 1.f);
            if (w > 0.f) fatom(&sWUs[cu], w);
        }
        // ---- stage 32x128 tile: float4 global, scalar LDS (2-way alias only) --
        for (int i = tid; i < 1024; i += 256) {
            int dd = i >> 3, p4 = (i & 7) << 2;
            size_t g = gb + (size_t)dd * 16384 + rem0 + p4;
            float4 x1 = *(const float4*)(fl1 + g);
            float4 x2 = *(const float4*)(fl2 + g);
            float* tp = &tile[dd * 33 + p4];
            tp[0] = 0.5f * (x1.x + x2.x);
            tp[1] = 0.5f * (x1.y + x2.y);
            tp[2] = 0.5f * (x1.z + x2.z);
            tp[3] = 0.5f * (x1.w + x2.w);
        }
        __syncthreads();
        // ---- transposed accumulate: zero atomics in hot loop ----
        float* aL = &accL[pg * (NCLS * DD) + d];
#pragma unroll
        for (int p = pg * 16; p < pg * 16 + 16; p++) {
            int c = sLab[p];
            aL[c * DD] += tile[d * 33 + p];
            float w = sW[p];
            if (w > 0.f) {                 // wave-uniform, rare: direct global
                size_t g = gb + (size_t)d * 16384 + rem0 + p;
                fatom(&W[OFF_SUMU + sCu[p] * DD + d], w * 0.5f * (fu1[g] + fu2[g]));
            }
        }
        __syncthreads();
    }
    // ---- flush per-block partials ----
    for (int i = tid; i < NCLS * DD; i += 256)
        fatom(&W[OFF_SUML + i], accL[i] + accL[NCLS * DD + i]);
    if (tid < NCLS) {
        fatom(&W[OFF_CNTL + tid], sCntL[tid]);
        fatom(&W[OFF_WSUMU + tid], sWUs[tid]);
        fatom(&W[OFF_CNTU + tid], sCntU[tid]);
    }
}

// ---------------- kD: finalize prototypes + memory update ----------------
// grid 19 x 128 (one block per class, one thread per d)
__global__ __launch_bounds__(128) void kD(const float* __restrict__ mem,
                                          const unsigned char* __restrict__ minit,
                                          float* __restrict__ W) {
    int c = blockIdx.x, d = threadIdx.x;
    __shared__ float red[128];
    float cntL = W[OFF_CNTL + c], wsU = W[OFF_WSUMU + c], cntU = W[OFF_CNTU + c];
    bool plp = cntL >= 1.f, pup = cntU >= 1.f;
    float pl = W[OFF_SUML + c * DD + d] / (cntL + EPSV);
    float pu = W[OFF_SUMU + c * DD + d] / (wsU + EPSV);
    float merged = (plp && pup) ? (0.7f * pl + 0.3f * pu) : (plp ? pl : pu);

    red[d] = merged * merged; __syncthreads();
    for (int s = 64; s > 0; s >>= 1) { if (d < s) red[d] += red[d + s]; __syncthreads(); }
    float nrm = red[0];
    __syncthreads();
    float pn = merged / fmaxf(sqrtf(nrm), 1e-12f);

    float mo = mem[c * DD + d];
    float e = 0.999f * mo + 0.001f * pn;
    red[d] = e * e; __syncthreads();
    for (int s = 64; s > 0; s >>= 1) { if (d < s) red[d] += red[d + s]; __syncthreads(); }
    float ne = red[0];
    float ema = e / fmaxf(sqrtf(ne), 1e-12f);

    bool present = plp || pup;
    bool init = (minit[c] != 0);   // all-False input: zero bytes either dtype width
    float nm = present ? (init ? ema : pn) : mo;
    W[OFF_MEM + c * DD + d] = nm;
    if (d == 0) W[OFF_INIT + c] = (init || present) ? 1.f : 0.f;
}

// ---------------- kE: hard contrastive for 4 feats ----------------
__device__ __forceinline__ void pix_loss(const float dots[NCLS], float nn, int lab,
                                         const float* sInit, float& ce_acc, float& v_acc) {
    float inv = 5.0f / fmaxf(sqrtf(nn), 1e-12f);   // 1/TAU_HARD = 5
    float lg[NCLS];
#pragma unroll
    for (int c = 0; c < NCLS; c++) lg[c] = dots[c] * inv;
    float mx = lg[0];
#pragma unroll
    for (int c = 1; c < NCLS; c++) mx = fmaxf(mx, lg[c]);
    float s = 0.f;
#pragma unroll
    for (int c = 0; c < NCLS; c++) s += __expf(lg[c] - mx);
    float lse = mx + __logf(s);
    float ll = lg[0];
#pragma unroll
    for (int c = 1; c < NCLS; c++) if (c == lab) ll = lg[c];
    float vld = sInit[lab];
    ce_acc += vld * (lse - ll);
    v_acc += vld;
}

// grid (128, 4) x 256; thread handles pixels p0 and p0+256 of feat blockIdx.y
__global__ __launch_bounds__(256) void kE(const float* __restrict__ f0,
                                          const float* __restrict__ f1,
                                          const float* __restrict__ f2,
                                          const float* __restrict__ f3,
                                          const int* __restrict__ gt,
                                          float* __restrict__ W) {
    __shared__ __align__(16) float sMem[NCLS * DD];
    __shared__ float sInit[NCLS];
    __shared__ float redA[256], redB[256];
    int fid = blockIdx.y;
    const float* feat = (fid == 0) ? f0 : (fid == 1) ? f1 : (fid == 2) ? f2 : f3;
    for (int i = threadIdx.x; i < NCLS * DD; i += 256) sMem[i] = W[OFF_MEM + i];
    if (threadIdx.x < NCLS) sInit[threadIdx.x] = W[OFF_INIT + threadIdx.x];
    __syncthreads();

    int p0 = blockIdx.x * 512 + threadIdx.x;   // second pixel = p0 + 256 (same b)
    int b = p0 >> 14;
    int rem0 = p0 & 16383;
    const float* fp = feat + (size_t)b * 2097152 + rem0;

    float dots0[NCLS], dots1[NCLS];
#pragma unroll
    for (int c = 0; c < NCLS; c++) { dots0[c] = 0.f; dots1[c] = 0.f; }
    float n0 = 0.f, n1 = 0.f;

    for (int d0 = 0; d0 < DD; d0 += 8) {
        const float* fpp = fp + (size_t)d0 * 16384;
        float a[8], bb[8];
#pragma unroll
        for (int j = 0; j < 8; j++) {
            a[j]  = fpp[(size_t)j * 16384];
            bb[j] = fpp[(size_t)j * 16384 + 256];
        }
#pragma unroll
        for (int j = 0; j < 8; j++) { n0 += a[j] * a[j]; n1 += bb[j] * bb[j]; }
#pragma unroll
        for (int c = 0; c < NCLS; c++) {
            float4 m0 = *(const float4*)&sMem[c * DD + d0];
            float4 m1 = *(const float4*)&sMem[c * DD + d0 + 4];
            dots0[c] += a[0] * m0.x + a[1] * m0.y + a[2] * m0.z + a[3] * m0.w
                      + a[4] * m1.x + a[5] * m1.y + a[6] * m1.z + a[7] * m1.w;
            dots1[c] += bb[0] * m0.x + bb[1] * m0.y + bb[2] * m0.z + bb[3] * m0.w
                      + bb[4] * m1.x + bb[5] * m1.y + bb[6] * m1.z + bb[7] * m1.w;
        }
    }

    const int* pseudo = (const int*)(W + OFF_PSEUDO);
    int rem1 = rem0 + 256;
    int lab0 = (fid < 2) ? gt[b * 262144 + (rem0 >> 7) * 2048 + (rem0 & 127) * 4] : pseudo[p0];
    int lab1 = (fid < 2) ? gt[b * 262144 + (rem1 >> 7) * 2048 + (rem1 & 127) * 4] : pseudo[p0 + 256];

    float ce_acc = 0.f, v_acc = 0.f;
    pix_loss(dots0, n0, lab0, sInit, ce_acc, v_acc);
    pix_loss(dots1, n1, lab1, sInit, ce_acc, v_acc);

    redA[threadIdx.x] = ce_acc;
    redB[threadIdx.x] = v_acc;
    __syncthreads();
    for (int s = 128; s > 0; s >>= 1) {
        if (threadIdx.x < s) { redA[threadIdx.x] += redA[threadIdx.x + s]; redB[threadIdx.x] += redB[threadIdx.x + s]; }
        __syncthreads();
    }
    if (threadIdx.x == 0) {
        fatom(&W[OFF_CE + fid], redA[0]);
        fatom(&W[OFF_VALID + fid], redB[0]);
    }
}

// ---------------- kF: combine -> d_out[2] ----------------
__global__ void kF(float* __restrict__ out, const float* __restrict__ W) {
    if (threadIdx.x == 0 && blockIdx.x == 0) {
        float h[4];
#pragma unroll
        for (int i = 0; i < 4; i++) {
            float nv = W[OFF_VALID + i];
            h[i] = (nv > 0.f) ? W[OFF_CE + i] / fmaxf(nv, 1.f) : 0.f;
        }
        out[0] = 0.5f * (h[0] + h[1]) + 0.5f * (h[2] + h[3]);   // loss_dgpc
        out[1] = W[OFF_UCPS] * (1.0f / 1048576.0f);             // loss_ucps
    }
}

extern "C" void kernel_launch(void* const* d_in, const int* in_sizes, int n_in,
                              void* d_out, int out_size, void* d_ws, size_t ws_size,
                              hipStream_t stream) {
    const float* fl1 = (const float*)d_in[0];
    const float* fl2 = (const float*)d_in[1];
    const float* fu1 = (const float*)d_in[2];
    const float* fu2 = (const float*)d_in[3];
    // d_in[4], d_in[5] (logits_l1/l2) are unused by the reference
    const float* lu1 = (const float*)d_in[6];
    const float* lu2 = (const float*)d_in[7];
    const float* mem = (const float*)d_in[8];
    const int* gt = (const int*)d_in[9];
    const unsigned char* minit = (const unsigned char*)d_in[10];
    const int* cur = (const int*)d_in[11];
    const int* mxi = (const int*)d_in[12];
    float* W = (float*)d_ws;
    float* out = (float*)d_out;

    kZ<<<286, 256, 0, stream>>>(W, cur, mxi);
    kB<<<1024, 256, 0, stream>>>(lu1, lu2, W);
    kC<<<512, 256, 0, stream>>>(fl1, fl2, fu1, fu2, gt, W);
    kD<<<NCLS, 128, 0, stream>>>(mem, minit, W);
    kE<<<dim3(128, 4), 256, 0, stream>>>(fl1, fl2, fu1, fu2, gt, W);
    kF<<<1, 64, 0, stream>>>(out, W);
}